// Round 14
// baseline (332.474 us; speedup 1.0000x reference)
//
#include <hip/hip_runtime.h>
#include <stdint.h>

#define B_  256
#define T_  512
#define H_  128
#define NSW 6

typedef __bf16 bf2_t  __attribute__((ext_vector_type(2)));
typedef int    i32x4  __attribute__((ext_vector_type(4)));
typedef float  f32x4  __attribute__((ext_vector_type(4)));

#define LOG2E 1.4426950408889634f

// float -> bf16 round-to-nearest-even
__device__ __forceinline__ unsigned short f2bf(float f){
  unsigned u = __float_as_uint(f);
  unsigned r = u + 0x7FFFu + ((u >> 16) & 1u);
  return (unsigned short)(r >> 16);
}
__device__ __forceinline__ unsigned pack2(float a, float b){
  return (unsigned)f2bf(a) | ((unsigned)f2bf(b) << 16);
}
__device__ __forceinline__ float dot2bf(unsigned wpair, unsigned hpair, float acc){
  return __builtin_amdgcn_fdot2_f32_bf16(__builtin_bit_cast(bf2_t, wpair),
                                         __builtin_bit_cast(bf2_t, hpair), acc, false);
}
__device__ __forceinline__ void lds_barrier(){
  asm volatile("s_waitcnt lgkmcnt(0)\ns_barrier" ::: "memory");
}

// Per-row symmetric int8 quantization into MFMA B-fragment order for
// mfma_i32_16x16x64_i8 (W^T). Tile (s, g', w) covers rows i = 16w..16w+15 of
// gate g'; half m covers k = 64m..64m+63.
// uint4 idx = ((s*24 + g'*8 + w)*2 + m)*64 + q*16 + c holds int8 of
//   W_g'[s][i = 16w + c][k = m*64 + q*16 + e]  (byte e of word e>>2)
// A-side (h) uses the same (quad,byte)<->k convention -> any HW k-permutation
// cancels. scales[s*384 + g'*128 + i] = rowmax / (127*127)
__global__ __launch_bounds__(256) void pack_weights_i8(const float* __restrict__ Wr,
                                                       const float* __restrict__ Wz,
                                                       const float* __restrict__ Wn,
                                                       uint4* __restrict__ dst,
                                                       float* __restrict__ scales){
  int idx = blockIdx.x * 256 + threadIdx.x;     // (s, row384)
  if (idx >= NSW * 384) return;
  int s   = idx / 384;
  int row = idx % 384;
  int gp  = row >> 7;                            // gate 0..2
  int i   = row & 127;                           // output row within gate
  const float* W = (gp == 0) ? Wr : (gp == 1) ? Wz : Wn;
  const float* src = W + (size_t)s * (H_*H_) + (size_t)i * H_;
  float amax = 0.f;
  for (int j = 0; j < H_; ++j) amax = fmaxf(amax, fabsf(src[j]));
  amax = fmaxf(amax, 1e-20f);
  float inv = 127.f / amax;
  scales[idx] = amax / 16129.f;                 // amax / 127^2
  int w = i >> 4, c = i & 15;
  for (int m = 0; m < 2; ++m){
    for (int q = 0; q < 4; ++q){
      unsigned bw[4] = {0, 0, 0, 0};
      for (int e = 0; e < 16; ++e){
        int k = m * 64 + q * 16 + e;
        int v = (int)rintf(src[k] * inv);
        v = v > 127 ? 127 : (v < -127 ? -127 : v);
        bw[e >> 2] |= ((unsigned)(v & 0xFF)) << (8 * (e & 3));
      }
      dst[((size_t)((s * 24 + gp * 8 + w) * 2 + m)) * 64 + q * 16 + c] =
        make_uint4(bw[0], bw[1], bw[2], bw[3]);
    }
  }
}

// 512 threads = 8 waves. Transposed MFMA: A = h (row 0 only), B = W^T.
// Round-14 = round-12 base (best, 247us counter) + PAIRED deferred output
// write: hold hprev2 = h_{U-2}; at the top of every EVEN step write ONE b128
// {wo0*h_{U-2}, wo1*h_{U-2}, wo0*h_{U-1}, wo1*h_{U-1}} instead of a b64 every
// step -> deferred-write DS ops halve (DS cost is per-op, not per-byte —
// round-13 lesson). REDUCE re-indexed to 16 pair-rows x 32 lanes; safety
// unchanged (first s_po2[0] overwrite is behind step-0 AND step-1 barriers,
// both of which require all waves past REDUCE). Recurrence numerics identical;
// output sum f32-reassociated only.
__global__ __launch_bounds__(512, 2) void gru_run(const float* __restrict__ stim,
    const int*   __restrict__ swid,  const float* __restrict__ mask,
    const float* __restrict__ Win,   const float* __restrict__ binp,
    const float* __restrict__ b_hr,  const float* __restrict__ b_hz, const float* __restrict__ b_hn,
    const float* __restrict__ Wo,    const float* __restrict__ bo,
    const uint4* __restrict__ Wpk,   const float* __restrict__ Wsc,
    float* __restrict__ out)
{
  const int b   = blockIdx.x;
  const int tid = threadIdx.x;
  const int w   = tid >> 6;          // 0..7
  const int L   = tid & 63;

  __shared__ uint4          s_stim2[T_];            // 8 KB   bf16 stim pairs
  __shared__ unsigned       s_sm[T_];               // 2 KB   {bf16 mask <<16 | sid}
  __shared__ __align__(16) float2 s_brz[NSW][H_];     // 6 KB   {b_hr, b_hz} per (s,row)
  __shared__ __align__(16) f32x4  s_scl4[NSW][H_];    // 12 KB  pre-scaled {-k*scl_r,-k*scl_z,2k*scl_n,2k*b_hn}
  __shared__ __align__(16) f32x4  s_xt[32][H_];       // 64 KB  pre-scaled x-projection chunk
  __shared__ __align__(16) f32x4  s_po2[16][H_];      // 32 KB  PAIRED output partials
  __shared__ __align__(16) char   s_hb8[2][H_];       // linear int8 h slots

  // ---- init LDS ----
  for (int k = tid; k < T_; k += 512){
    const float* sp = stim + (size_t)b * T_ * 8 + (size_t)k * 8;
    uint4 o;
    o.x = pack2(sp[0], sp[1]); o.y = pack2(sp[2], sp[3]);
    o.z = pack2(sp[4], sp[5]); o.w = pack2(sp[6], sp[7]);
    s_stim2[k] = o;
    int ss = swid[(size_t)b * T_ + k];
    ss = ss < 0 ? 0 : (ss > NSW - 1 ? NSW - 1 : ss);
    s_sm[k] = ((unsigned)f2bf(mask[(size_t)b * T_ + k]) << 16) | (unsigned)ss;
  }
  for (int k = tid; k < NSW * H_; k += 512){
    int s = k >> 7, i = k & 127;
    s_brz[s][i]  = make_float2(b_hr[s * H_ + i], b_hz[s * H_ + i]);
    s_scl4[s][i] = (f32x4){-LOG2E * Wsc[s * 384 + i],
                           -LOG2E * Wsc[s * 384 + 128 + i],
                           2.f * LOG2E * Wsc[s * 384 + 256 + i],
                           2.f * LOG2E * b_hn[s * H_ + i]};
  }
  if (tid < 64) ((int*)s_hb8)[tid] = 0;          // zero both int8 slots

  const int hi_p = tid & 127;
  const int tq   = tid >> 7;                     // 0..3: covers t-offsets tq*8..tq*8+7

  const bool colv = (L & 15) == 0;
  const int  quad = L >> 4;
  const int  hi_  = 16 * w + (L & 15);
  float* outp = out + (size_t)b * T_ * 2;
  const float bo0 = bo[0], bo1 = bo[1];
  float wo0r = 0.f, wo1r = 0.f;
  if (L < 16){ wo0r = Wo[hi_]; wo1r = Wo[H_ + hi_]; }

  // ---- preload ALL 6 switch-sets' B fragments (W^T). volatile: cannot be
  //      sunk into the loop or rematerialized. 6 x 6 x uint4 = 144 regs (AGPR).
  uint4 Bf[6][6];
  #pragma unroll
  for (int s = 0; s < 6; ++s){
    #pragma unroll
    for (int gp = 0; gp < 3; ++gp){
      #pragma unroll
      for (int m = 0; m < 2; ++m){
        const volatile unsigned* vp =
          (const volatile unsigned*)(Wpk + ((size_t)((s * 24 + gp * 8 + w) * 2 + m)) * 64 + L);
        Bf[s][gp*2+m].x = vp[0];
        Bf[s][gp*2+m].y = vp[1];
        Bf[s][gp*2+m].z = vp[2];
        Bf[s][gp*2+m].w = vp[3];
      }
    }
  }

  __syncthreads();

  float hprev = 0.f, hprev2 = 0.f;
  int   smv = 0;                       // 32 steps of {mask|sid}, lane (L&31) = step
  // persistent rotated operand sets (A = even steps, B = odd steps) and
  // persistent exec-masked registers (zeros written once).
  uint4 blo = {0, 0, 0, 0}, bhi = {0, 0, 0, 0};
  f32x4 xtvA = {0.f,0.f,0.f,0.f}, xtvB = {0.f,0.f,0.f,0.f};
  f32x4 sclvA = {0.f,0.f,0.f,0.f}, sclvB = {0.f,0.f,0.f,0.f};
  float mtA = 0.f, mtB = 0.f;
  int   scA = 0,  scB = 0;

#define MFMA64(A_, B_, C_) __builtin_amdgcn_mfma_i32_16x16x64_i8( \
    __builtin_bit_cast(i32x4, (A_)), __builtin_bit_cast(i32x4, (B_)), (C_), 0, 0, 0)
#define MM(S)                                                                  \
    { i32x4 a; const i32x4 zz = {0,0,0,0};                                     \
      a = MFMA64(blo, Bf[S][0], zz); a = MFMA64(bhi, Bf[S][1], a); acx0 = a.x; \
      a = MFMA64(blo, Bf[S][2], zz); a = MFMA64(bhi, Bf[S][3], a); acx1 = a.x; \
      a = MFMA64(blo, Bf[S][4], zz); a = MFMA64(bhi, Bf[S][5], a); acx2 = a.x; }

// One recurrence step. Uses current operand set {XC,SCV,MC,CC}; prefetches
// step U+1's h-independent operands into {XN,SN,MN,CN} (PF=1). At EVEN steps
// U>=2, the PAIRED deferred b128 write for steps (U-2, U-1) lands in the
// post-barrier shadow (hprev2 == h_{U-2}, hprev == h_{U-1}).
#define STEP(U, XC, SCV, MC, CC, XN, SN, MN, CN, PF)                           \
  {                                                                            \
    const char* hsrc = &s_hb8[((U) + 1) & 1][0];                               \
    if (colv){                                                                 \
      blo = *(const uint4*)(hsrc + quad * 16);                                 \
      bhi = *(const uint4*)(hsrc + 64 + quad * 16);                            \
    }                                                                          \
    if ((((U) & 1) == 0) && (U) > 0 && L < 16){                                \
      f32x4 pv;                                                                \
      pv.x = wo0r * hprev2; pv.y = wo1r * hprev2;                              \
      pv.z = wo0r * hprev;  pv.w = wo1r * hprev;                               \
      s_po2[((U) - 2) >> 1][hi_] = pv;                                         \
    }                                                                          \
    if (PF){                                                                   \
      int smn = __builtin_amdgcn_readlane(smv, (U) + 1);                       \
      CN = smn & 0xFFFF;                                                       \
      MN = __uint_as_float((unsigned)smn & 0xFFFF0000u);                       \
      if (L < 16){                                                             \
        XN = s_xt[(U) + 1][hi_];                                               \
        SN = s_scl4[CN][hi_];                                                  \
      }                                                                        \
    }                                                                          \
    int acx0, acx1, acx2;                                                      \
    switch (CC){                                                               \
      case 0: MM(0); break;                                                    \
      case 1: MM(1); break;                                                    \
      case 2: MM(2); break;                                                    \
      case 3: MM(3); break;                                                    \
      case 4: MM(4); break;                                                    \
      default: MM(5); break;                                                   \
    }                                                                          \
    if (L < 16){                                                               \
      float ar = fmaf((float)acx0, SCV.x, XC.x);   /* -log2e*(pre-act r) */    \
      float az = fmaf((float)acx1, SCV.y, XC.y);   /* -log2e*(pre-act z) */    \
      float an = fmaf((float)acx2, SCV.z, SCV.w);  /* 2log2e*(Wh*scl + b_n) */ \
      float r = __builtin_amdgcn_rcpf(1.f + __builtin_amdgcn_exp2f(ar));       \
      float z = __builtin_amdgcn_rcpf(1.f + __builtin_amdgcn_exp2f(az));       \
      float e = __builtin_amdgcn_exp2f(fmaf(r, an, XC.z));                     \
      float n = fmaf(-2.f, __builtin_amdgcn_rcpf(e + 1.f), 1.f);               \
      float hnew = fmaf(z, hprev - n, n);                                      \
      float ho   = fmaf(MC, hnew - hprev, hprev);                              \
      hprev2 = hprev;                                                          \
      hprev  = ho;                                                             \
      s_hb8[(U) & 1][hi_] = (char)(int)rintf(ho * 127.f);                      \
    }                                                                          \
    lds_barrier();                                                             \
  }

// pair-row reduce: 16 pair-rows x 32 lanes; each f32x4 holds two timesteps'
// {p0,p1}; one aligned dwordx4 store covers both outputs.
#define REDUCE(TBASE)                                                          \
  {                                                                            \
    int tp = tid >> 5;                                                         \
    int q  = tid & 31;                                                         \
    const f32x4* prow = (const f32x4*)&s_po2[tp][0];                           \
    f32x4 a0 = prow[q], a1 = prow[q+32], a2 = prow[q+64], a3 = prow[q+96];     \
    f32x4 sv = (a0 + a1) + (a2 + a3);                                          \
    sv.x += __shfl_down(sv.x, 16, 32); sv.y += __shfl_down(sv.y, 16, 32);      \
    sv.z += __shfl_down(sv.z, 16, 32); sv.w += __shfl_down(sv.w, 16, 32);      \
    sv.x += __shfl_down(sv.x,  8, 32); sv.y += __shfl_down(sv.y,  8, 32);      \
    sv.z += __shfl_down(sv.z,  8, 32); sv.w += __shfl_down(sv.w,  8, 32);      \
    sv.x += __shfl_down(sv.x,  4, 32); sv.y += __shfl_down(sv.y,  4, 32);      \
    sv.z += __shfl_down(sv.z,  4, 32); sv.w += __shfl_down(sv.w,  4, 32);      \
    sv.x += __shfl_down(sv.x,  2, 32); sv.y += __shfl_down(sv.y,  2, 32);      \
    sv.z += __shfl_down(sv.z,  2, 32); sv.w += __shfl_down(sv.w,  2, 32);      \
    sv.x += __shfl_down(sv.x,  1, 32); sv.y += __shfl_down(sv.y,  1, 32);      \
    sv.z += __shfl_down(sv.z,  1, 32); sv.w += __shfl_down(sv.w,  1, 32);      \
    if (q == 0){                                                               \
      f32x4 o;                                                                 \
      o.x = sv.x + bo0; o.y = sv.y + bo1;                                      \
      o.z = sv.z + bo0; o.w = sv.w + bo1;                                      \
      *(f32x4*)&outp[((TBASE) + 2 * tp) * 2] = o;                              \
    }                                                                          \
  }

  #pragma unroll 1
  for (int ch = 0; ch < 16; ++ch){
    const int t0 = ch << 5;

    // paired deferred write for steps (30,31) of the PREVIOUS chunk
    // (hprev2 == h_30, hprev == h_31). At ch==0: zeros, dead (REDUCE skipped).
    if (L < 16){
      f32x4 pv;
      pv.x = wo0r * hprev2; pv.y = wo1r * hprev2;
      pv.z = wo0r * hprev;  pv.w = wo1r * hprev;
      s_po2[15][hi_] = pv;
    }

    // ---- chunk boundary: build x̃ chunk (pre-scaled, biases folded) ----
    {
      unsigned winp[3][4];
      float    binr[3];
      #pragma unroll
      for (int gp = 0; gp < 3; ++gp){
        int row = gp * 128 + hi_p;
        #pragma unroll
        for (int e = 0; e < 4; ++e)
          winp[gp][e] = pack2(Win[(size_t)row * 8 + 2*e], Win[(size_t)row * 8 + 2*e + 1]);
        binr[gp] = binp[row];
      }
      #pragma unroll
      for (int j = 0; j < 8; ++j){
        int tt = t0 + tq * 8 + j;
        uint4 sp = s_stim2[tt];
        int sid_tt = (int)(s_sm[tt] & 0xFFFFu);        // wave-uniform
        float2 brz = s_brz[sid_tt][hi_p];
        float x0 = binr[0];
        x0 = dot2bf(winp[0][0], sp.x, x0); x0 = dot2bf(winp[0][1], sp.y, x0);
        x0 = dot2bf(winp[0][2], sp.z, x0); x0 = dot2bf(winp[0][3], sp.w, x0);
        float x1 = binr[1];
        x1 = dot2bf(winp[1][0], sp.x, x1); x1 = dot2bf(winp[1][1], sp.y, x1);
        x1 = dot2bf(winp[1][2], sp.z, x1); x1 = dot2bf(winp[1][3], sp.w, x1);
        float x2 = binr[2];
        x2 = dot2bf(winp[2][0], sp.x, x2); x2 = dot2bf(winp[2][1], sp.y, x2);
        x2 = dot2bf(winp[2][2], sp.z, x2); x2 = dot2bf(winp[2][3], sp.w, x2);
        f32x4 xv;
        xv.x = -LOG2E * (x0 + brz.x);       // r: bias folded + exp2 pre-scale
        xv.y = -LOG2E * (x1 + brz.y);       // z: bias folded + exp2 pre-scale
        xv.z = (2.f * LOG2E) * x2;          // n: exp2 pre-scale (b_n in sclv.w)
        xv.w = 0.f;
        s_xt[tq * 8 + j][hi_p] = xv;
      }
    }
    lds_barrier();                 // x̃ chunk + deferred pair-15 visible

    // previous chunk's outputs (after the barrier; safe vs the first in-chunk
    // s_po2[0] write, which is behind the step-0 AND step-1 barriers)
    if (ch > 0) REDUCE(t0 - 32);

    smv = (int)s_sm[t0 + (L & 31)];              // this chunk's {mask|sid}

    // prologue: step-0 operands (A set)
    {
      int sm0 = __builtin_amdgcn_readlane(smv, 0);
      scA = sm0 & 0xFFFF;
      mtA = __uint_as_float((unsigned)sm0 & 0xFFFF0000u);
      if (L < 16){
        xtvA  = s_xt[0][hi_];
        sclvA = s_scl4[scA][hi_];
      }
    }

    // steps 0..23: 3 groups of unroll-8 (PF always true)
    #pragma unroll 1
    for (int g = 0; g < 3; ++g){
      const int u0 = g << 3;
      #pragma unroll
      for (int p = 0; p < 4; ++p){
        STEP(u0 + 2*p,     xtvA, sclvA, mtA, scA, xtvB, sclvB, mtB, scB, 1);
        STEP(u0 + 2*p + 1, xtvB, sclvB, mtB, scB, xtvA, sclvA, mtA, scA, 1);
      }
    }
    // steps 24..31: fully unrolled tail; step 31 has no prefetch
    #pragma unroll
    for (int p = 0; p < 3; ++p){
      STEP(24 + 2*p,     xtvA, sclvA, mtA, scA, xtvB, sclvB, mtB, scB, 1);
      STEP(24 + 2*p + 1, xtvB, sclvB, mtB, scB, xtvA, sclvA, mtA, scA, 1);
    }
    STEP(30, xtvA, sclvA, mtA, scA, xtvB, sclvB, mtB, scB, 1);
    STEP(31, xtvB, sclvB, mtB, scB, xtvA, sclvA, mtA, scA, 0);
  }

  // final chunk: deferred pair (30,31), then reduce
  if (L < 16){
    f32x4 pv;
    pv.x = wo0r * hprev2; pv.y = wo1r * hprev2;
    pv.z = wo0r * hprev;  pv.w = wo1r * hprev;
    s_po2[15][hi_] = pv;
  }
  lds_barrier();
  REDUCE(T_ - 32);
#undef REDUCE
#undef STEP
#undef MM
#undef MFMA64
}

extern "C" void kernel_launch(void* const* d_in, const int* in_sizes, int n_in,
                              void* d_out, int out_size, void* d_ws, size_t ws_size,
                              hipStream_t stream) {
  const float* stim = (const float*)d_in[0];
  const int*   swid = (const int*)  d_in[1];
  const float* mask = (const float*)d_in[2];
  const float* Win  = (const float*)d_in[3];
  const float* binp = (const float*)d_in[4];
  const float* Whr  = (const float*)d_in[5];
  const float* Whz  = (const float*)d_in[6];
  const float* Whn  = (const float*)d_in[7];
  const float* bhr  = (const float*)d_in[8];
  const float* bhz  = (const float*)d_in[9];
  const float* bhn  = (const float*)d_in[10];
  const float* Wo   = (const float*)d_in[11];
  const float* bo   = (const float*)d_in[12];

  uint4* wpk = (uint4*)d_ws;                       // 294912 B packed int8 frags
  float* wsc = (float*)((char*)d_ws + 294912);     // 9216 B row scales

  pack_weights_i8<<<9, 256, 0, stream>>>(Whr, Whz, Whn, wpk, wsc);
  gru_run<<<B_, 512, 0, stream>>>(stim, swid, mask, Win, binp,
                                  bhr, bhz, bhn, Wo, bo, wpk, wsc, (float*)d_out);
}

// Round 15
// 328.899 us; speedup vs baseline: 1.0109x; 1.0109x over previous
//
#include <hip/hip_runtime.h>
#include <stdint.h>

#define B_  256
#define T_  512
#define H_  128
#define NSW 6

typedef __bf16 bf2_t  __attribute__((ext_vector_type(2)));
typedef int    i32x4  __attribute__((ext_vector_type(4)));
typedef float  f32x4  __attribute__((ext_vector_type(4)));

#define LOG2E 1.4426950408889634f

// float -> bf16 round-to-nearest-even
__device__ __forceinline__ unsigned short f2bf(float f){
  unsigned u = __float_as_uint(f);
  unsigned r = u + 0x7FFFu + ((u >> 16) & 1u);
  return (unsigned short)(r >> 16);
}
__device__ __forceinline__ unsigned pack2(float a, float b){
  return (unsigned)f2bf(a) | ((unsigned)f2bf(b) << 16);
}
__device__ __forceinline__ float dot2bf(unsigned wpair, unsigned hpair, float acc){
  return __builtin_amdgcn_fdot2_f32_bf16(__builtin_bit_cast(bf2_t, wpair),
                                         __builtin_bit_cast(bf2_t, hpair), acc, false);
}
__device__ __forceinline__ void lds_barrier(){
  asm volatile("s_waitcnt lgkmcnt(0)\ns_barrier" ::: "memory");
}

// Per-row symmetric int8 quantization into MFMA B-fragment order for
// mfma_i32_16x16x64_i8 (W^T). Tile (s, g', w) covers rows i = 16w..16w+15 of
// gate g'; half m covers k = 64m..64m+63.
// uint4 idx = ((s*24 + g'*8 + w)*2 + m)*64 + q*16 + c holds int8 of
//   W_g'[s][i = 16w + c][k = m*64 + q*16 + e]  (byte e of word e>>2)
// A-side (h) uses the same (quad,byte)<->k convention -> any HW k-permutation
// cancels. scales[s*384 + g'*128 + i] = rowmax / (127*127)
__global__ __launch_bounds__(256) void pack_weights_i8(const float* __restrict__ Wr,
                                                       const float* __restrict__ Wz,
                                                       const float* __restrict__ Wn,
                                                       uint4* __restrict__ dst,
                                                       float* __restrict__ scales){
  int idx = blockIdx.x * 256 + threadIdx.x;     // (s, row384)
  if (idx >= NSW * 384) return;
  int s   = idx / 384;
  int row = idx % 384;
  int gp  = row >> 7;                            // gate 0..2
  int i   = row & 127;                           // output row within gate
  const float* W = (gp == 0) ? Wr : (gp == 1) ? Wz : Wn;
  const float* src = W + (size_t)s * (H_*H_) + (size_t)i * H_;
  float amax = 0.f;
  for (int j = 0; j < H_; ++j) amax = fmaxf(amax, fabsf(src[j]));
  amax = fmaxf(amax, 1e-20f);
  float inv = 127.f / amax;
  scales[idx] = amax / 16129.f;                 // amax / 127^2
  int w = i >> 4, c = i & 15;
  for (int m = 0; m < 2; ++m){
    for (int q = 0; q < 4; ++q){
      unsigned bw[4] = {0, 0, 0, 0};
      for (int e = 0; e < 16; ++e){
        int k = m * 64 + q * 16 + e;
        int v = (int)rintf(src[k] * inv);
        v = v > 127 ? 127 : (v < -127 ? -127 : v);
        bw[e >> 2] |= ((unsigned)(v & 0xFF)) << (8 * (e & 3));
      }
      dst[((size_t)((s * 24 + gp * 8 + w) * 2 + m)) * 64 + q * 16 + c] =
        make_uint4(bw[0], bw[1], bw[2], bw[3]);
    }
  }
}

// 512 threads = 8 waves. Transposed MFMA: A = h (row 0 only), B = W^T.
// SESSION-BEST structure (round 12, 247us counter). Latency-locked floor:
// full weight residency (144 AGPR/wave) pins occupancy at 2 waves/SIMD
// (measured VGPR-pool scaling, m69); the per-step serial skeleton
// (barrier -> h LDS round-trip -> dependent MFMA pair -> 8-op gate chain ->
// write+drain -> barrier) is ~600cy irreducible; DS-throughput and VALU-issue
// cuts beyond this point measured neutral (rounds 13-14).
__global__ __launch_bounds__(512, 2) void gru_run(const float* __restrict__ stim,
    const int*   __restrict__ swid,  const float* __restrict__ mask,
    const float* __restrict__ Win,   const float* __restrict__ binp,
    const float* __restrict__ b_hr,  const float* __restrict__ b_hz, const float* __restrict__ b_hn,
    const float* __restrict__ Wo,    const float* __restrict__ bo,
    const uint4* __restrict__ Wpk,   const float* __restrict__ Wsc,
    float* __restrict__ out)
{
  const int b   = blockIdx.x;
  const int tid = threadIdx.x;
  const int w   = tid >> 6;          // 0..7
  const int L   = tid & 63;

  __shared__ uint4          s_stim2[T_];            // 8 KB   bf16 stim pairs
  __shared__ unsigned       s_sm[T_];               // 2 KB   {bf16 mask <<16 | sid}
  __shared__ __align__(16) float2 s_brz[NSW][H_];     // 6 KB   {b_hr, b_hz} per (s,row)
  __shared__ __align__(16) f32x4  s_scl4[NSW][H_];    // 12 KB  pre-scaled {-k*scl_r,-k*scl_z,2k*scl_n,2k*b_hn}
  __shared__ __align__(16) f32x4  s_xt[32][H_];       // 64 KB  pre-scaled x-projection chunk
  __shared__ __align__(16) float2 s_po[32][130];      // 32.5 KB output partials (padded)
  __shared__ __align__(16) char   s_hb8[2][H_];       // linear int8 h slots

  // ---- init LDS ----
  for (int k = tid; k < T_; k += 512){
    const float* sp = stim + (size_t)b * T_ * 8 + (size_t)k * 8;
    uint4 o;
    o.x = pack2(sp[0], sp[1]); o.y = pack2(sp[2], sp[3]);
    o.z = pack2(sp[4], sp[5]); o.w = pack2(sp[6], sp[7]);
    s_stim2[k] = o;
    int ss = swid[(size_t)b * T_ + k];
    ss = ss < 0 ? 0 : (ss > NSW - 1 ? NSW - 1 : ss);
    s_sm[k] = ((unsigned)f2bf(mask[(size_t)b * T_ + k]) << 16) | (unsigned)ss;
  }
  for (int k = tid; k < NSW * H_; k += 512){
    int s = k >> 7, i = k & 127;
    s_brz[s][i]  = make_float2(b_hr[s * H_ + i], b_hz[s * H_ + i]);
    s_scl4[s][i] = (f32x4){-LOG2E * Wsc[s * 384 + i],
                           -LOG2E * Wsc[s * 384 + 128 + i],
                           2.f * LOG2E * Wsc[s * 384 + 256 + i],
                           2.f * LOG2E * b_hn[s * H_ + i]};
  }
  if (tid < 64) ((int*)s_hb8)[tid] = 0;          // zero both int8 slots

  const int hi_p = tid & 127;
  const int tq   = tid >> 7;                     // 0..3: covers t-offsets tq*8..tq*8+7

  const bool colv = (L & 15) == 0;
  const int  quad = L >> 4;
  const int  hi_  = 16 * w + (L & 15);
  float* outp = out + (size_t)b * T_ * 2;
  const float bo0 = bo[0], bo1 = bo[1];
  float wo0r = 0.f, wo1r = 0.f;
  if (L < 16){ wo0r = Wo[hi_]; wo1r = Wo[H_ + hi_]; }

  // ---- preload ALL 6 switch-sets' B fragments (W^T). volatile: cannot be
  //      sunk into the loop or rematerialized. 6 x 6 x uint4 = 144 regs (AGPR).
  uint4 Bf[6][6];
  #pragma unroll
  for (int s = 0; s < 6; ++s){
    #pragma unroll
    for (int gp = 0; gp < 3; ++gp){
      #pragma unroll
      for (int m = 0; m < 2; ++m){
        const volatile unsigned* vp =
          (const volatile unsigned*)(Wpk + ((size_t)((s * 24 + gp * 8 + w) * 2 + m)) * 64 + L);
        Bf[s][gp*2+m].x = vp[0];
        Bf[s][gp*2+m].y = vp[1];
        Bf[s][gp*2+m].z = vp[2];
        Bf[s][gp*2+m].w = vp[3];
      }
    }
  }

  __syncthreads();

  float hprev = 0.f;
  int   smv = 0;                       // 32 steps of {mask|sid}, lane (L&31) = step
  // persistent rotated operand sets (A = even steps, B = odd steps) and
  // persistent exec-masked registers (zeros written once).
  uint4 blo = {0, 0, 0, 0}, bhi = {0, 0, 0, 0};
  f32x4 xtvA = {0.f,0.f,0.f,0.f}, xtvB = {0.f,0.f,0.f,0.f};
  f32x4 sclvA = {0.f,0.f,0.f,0.f}, sclvB = {0.f,0.f,0.f,0.f};
  float mtA = 0.f, mtB = 0.f;
  int   scA = 0,  scB = 0;

#define MFMA64(A_, B_, C_) __builtin_amdgcn_mfma_i32_16x16x64_i8( \
    __builtin_bit_cast(i32x4, (A_)), __builtin_bit_cast(i32x4, (B_)), (C_), 0, 0, 0)
#define MM(S)                                                                  \
    { i32x4 a; const i32x4 zz = {0,0,0,0};                                     \
      a = MFMA64(blo, Bf[S][0], zz); a = MFMA64(bhi, Bf[S][1], a); acx0 = a.x; \
      a = MFMA64(blo, Bf[S][2], zz); a = MFMA64(bhi, Bf[S][3], a); acx1 = a.x; \
      a = MFMA64(blo, Bf[S][4], zz); a = MFMA64(bhi, Bf[S][5], a); acx2 = a.x; }

// One recurrence step. Uses current operand set {XC,SCV,MC,CC}; prefetches
// step U+1's h-independent operands into {XN,SN,MN,CN} (PF=1). The DEFERRED
// s_po write for step U-1 (hprev == h_{U-1}) lands in the post-barrier shadow.
#define STEP(U, XC, SCV, MC, CC, XN, SN, MN, CN, PF)                           \
  {                                                                            \
    const char* hsrc = &s_hb8[((U) + 1) & 1][0];                               \
    if (colv){                                                                 \
      blo = *(const uint4*)(hsrc + quad * 16);                                 \
      bhi = *(const uint4*)(hsrc + 64 + quad * 16);                            \
    }                                                                          \
    if ((U) > 0 && L < 16)                                                     \
      s_po[(U) - 1][hi_] = make_float2(wo0r * hprev, wo1r * hprev);            \
    if (PF){                                                                   \
      int smn = __builtin_amdgcn_readlane(smv, (U) + 1);                       \
      CN = smn & 0xFFFF;                                                       \
      MN = __uint_as_float((unsigned)smn & 0xFFFF0000u);                       \
      if (L < 16){                                                             \
        XN = s_xt[(U) + 1][hi_];                                               \
        SN = s_scl4[CN][hi_];                                                  \
      }                                                                        \
    }                                                                          \
    int acx0, acx1, acx2;                                                      \
    switch (CC){                                                               \
      case 0: MM(0); break;                                                    \
      case 1: MM(1); break;                                                    \
      case 2: MM(2); break;                                                    \
      case 3: MM(3); break;                                                    \
      case 4: MM(4); break;                                                    \
      default: MM(5); break;                                                   \
    }                                                                          \
    if (L < 16){                                                               \
      float ar = fmaf((float)acx0, SCV.x, XC.x);   /* -log2e*(pre-act r) */    \
      float az = fmaf((float)acx1, SCV.y, XC.y);   /* -log2e*(pre-act z) */    \
      float an = fmaf((float)acx2, SCV.z, SCV.w);  /* 2log2e*(Wh*scl + b_n) */ \
      float r = __builtin_amdgcn_rcpf(1.f + __builtin_amdgcn_exp2f(ar));       \
      float z = __builtin_amdgcn_rcpf(1.f + __builtin_amdgcn_exp2f(az));       \
      float e = __builtin_amdgcn_exp2f(fmaf(r, an, XC.z));                     \
      float n = fmaf(-2.f, __builtin_amdgcn_rcpf(e + 1.f), 1.f);               \
      float hnew = fmaf(z, hprev - n, n);                                      \
      float ho   = fmaf(MC, hnew - hprev, hprev);                              \
      hprev = ho;                                                              \
      s_hb8[(U) & 1][hi_] = (char)(int)rintf(ho * 127.f);                      \
    }                                                                          \
    lds_barrier();                                                             \
  }

#define REDUCE(TBASE)                                                          \
  {                                                                            \
    int tp = tid >> 4;                                                         \
    int q  = tid & 15;                                                         \
    const f32x4* prow = (const f32x4*)&s_po[tp][0];                            \
    f32x4 a0 = prow[q], a1 = prow[q+16], a2 = prow[q+32], a3 = prow[q+48];     \
    f32x4 sv = (a0 + a1) + (a2 + a3);                                          \
    float p0 = sv.x + sv.z, p1 = sv.y + sv.w;                                  \
    p0 += __shfl_down(p0, 8, 16); p1 += __shfl_down(p1, 8, 16);                \
    p0 += __shfl_down(p0, 4, 16); p1 += __shfl_down(p1, 4, 16);                \
    p0 += __shfl_down(p0, 2, 16); p1 += __shfl_down(p1, 2, 16);                \
    p0 += __shfl_down(p0, 1, 16); p1 += __shfl_down(p1, 1, 16);                \
    if (q == 0)                                                                \
      *(float2*)&outp[((TBASE) + tp) * 2] = make_float2(p0 + bo0, p1 + bo1);   \
  }

  #pragma unroll 1
  for (int ch = 0; ch < 16; ++ch){
    const int t0 = ch << 5;

    // deferred step-31 partial of the PREVIOUS chunk (hprev == h_31).
    // At ch==0 this writes zeros to s_po[31] -- dead (REDUCE skipped).
    if (L < 16)
      s_po[31][hi_] = make_float2(wo0r * hprev, wo1r * hprev);

    // ---- chunk boundary: build x̃ chunk (pre-scaled, biases folded) ----
    {
      unsigned winp[3][4];
      float    binr[3];
      #pragma unroll
      for (int gp = 0; gp < 3; ++gp){
        int row = gp * 128 + hi_p;
        #pragma unroll
        for (int e = 0; e < 4; ++e)
          winp[gp][e] = pack2(Win[(size_t)row * 8 + 2*e], Win[(size_t)row * 8 + 2*e + 1]);
        binr[gp] = binp[row];
      }
      #pragma unroll
      for (int j = 0; j < 8; ++j){
        int tt = t0 + tq * 8 + j;
        uint4 sp = s_stim2[tt];
        int sid_tt = (int)(s_sm[tt] & 0xFFFFu);        // wave-uniform
        float2 brz = s_brz[sid_tt][hi_p];
        float x0 = binr[0];
        x0 = dot2bf(winp[0][0], sp.x, x0); x0 = dot2bf(winp[0][1], sp.y, x0);
        x0 = dot2bf(winp[0][2], sp.z, x0); x0 = dot2bf(winp[0][3], sp.w, x0);
        float x1 = binr[1];
        x1 = dot2bf(winp[1][0], sp.x, x1); x1 = dot2bf(winp[1][1], sp.y, x1);
        x1 = dot2bf(winp[1][2], sp.z, x1); x1 = dot2bf(winp[1][3], sp.w, x1);
        float x2 = binr[2];
        x2 = dot2bf(winp[2][0], sp.x, x2); x2 = dot2bf(winp[2][1], sp.y, x2);
        x2 = dot2bf(winp[2][2], sp.z, x2); x2 = dot2bf(winp[2][3], sp.w, x2);
        f32x4 xv;
        xv.x = -LOG2E * (x0 + brz.x);       // r: bias folded + exp2 pre-scale
        xv.y = -LOG2E * (x1 + brz.y);       // z: bias folded + exp2 pre-scale
        xv.z = (2.f * LOG2E) * x2;          // n: exp2 pre-scale (b_n in sclv.w)
        xv.w = 0.f;
        s_xt[tq * 8 + j][hi_p] = xv;
      }
    }
    lds_barrier();                 // x̃ chunk + deferred s_po[31] visible

    // previous chunk's outputs (after the barrier; safe vs step-1's s_po[0]
    // write, which is gated by step-0's barrier)
    if (ch > 0) REDUCE(t0 - 32);

    smv = (int)s_sm[t0 + (L & 31)];              // this chunk's {mask|sid}

    // prologue: step-0 operands (A set)
    {
      int sm0 = __builtin_amdgcn_readlane(smv, 0);
      scA = sm0 & 0xFFFF;
      mtA = __uint_as_float((unsigned)sm0 & 0xFFFF0000u);
      if (L < 16){
        xtvA  = s_xt[0][hi_];
        sclvA = s_scl4[scA][hi_];
      }
    }

    // steps 0..23: 3 groups of unroll-8 (PF always true)
    #pragma unroll 1
    for (int g = 0; g < 3; ++g){
      const int u0 = g << 3;
      #pragma unroll
      for (int p = 0; p < 4; ++p){
        STEP(u0 + 2*p,     xtvA, sclvA, mtA, scA, xtvB, sclvB, mtB, scB, 1);
        STEP(u0 + 2*p + 1, xtvB, sclvB, mtB, scB, xtvA, sclvA, mtA, scA, 1);
      }
    }
    // steps 24..31: fully unrolled tail; step 31 has no prefetch
    #pragma unroll
    for (int p = 0; p < 3; ++p){
      STEP(24 + 2*p,     xtvA, sclvA, mtA, scA, xtvB, sclvB, mtB, scB, 1);
      STEP(24 + 2*p + 1, xtvB, sclvB, mtB, scB, xtvA, sclvA, mtA, scA, 1);
    }
    STEP(30, xtvA, sclvA, mtA, scA, xtvB, sclvB, mtB, scB, 1);
    STEP(31, xtvB, sclvB, mtB, scB, xtvA, sclvA, mtA, scA, 0);
  }

  // final chunk: deferred step-31 partial, then reduce
  if (L < 16)
    s_po[31][hi_] = make_float2(wo0r * hprev, wo1r * hprev);
  lds_barrier();
  REDUCE(T_ - 32);
#undef REDUCE
#undef STEP
#undef MM
#undef MFMA64
}

extern "C" void kernel_launch(void* const* d_in, const int* in_sizes, int n_in,
                              void* d_out, int out_size, void* d_ws, size_t ws_size,
                              hipStream_t stream) {
  const float* stim = (const float*)d_in[0];
  const int*   swid = (const int*)  d_in[1];
  const float* mask = (const float*)d_in[2];
  const float* Win  = (const float*)d_in[3];
  const float* binp = (const float*)d_in[4];
  const float* Whr  = (const float*)d_in[5];
  const float* Whz  = (const float*)d_in[6];
  const float* Whn  = (const float*)d_in[7];
  const float* bhr  = (const float*)d_in[8];
  const float* bhz  = (const float*)d_in[9];
  const float* bhn  = (const float*)d_in[10];
  const float* Wo   = (const float*)d_in[11];
  const float* bo   = (const float*)d_in[12];

  uint4* wpk = (uint4*)d_ws;                       // 294912 B packed int8 frags
  float* wsc = (float*)((char*)d_ws + 294912);     // 9216 B row scales

  pack_weights_i8<<<9, 256, 0, stream>>>(Whr, Whz, Whn, wpk, wsc);
  gru_run<<<B_, 512, 0, stream>>>(stim, swid, mask, Win, binp,
                                  bhr, bhz, bhn, Wo, bo, wpk, wsc, (float*)d_out);
}